// Round 9
// baseline (189.263 us; speedup 1.0000x reference)
//
#include <hip/hip_runtime.h>
#include <math.h>

// Problem constants
#define DD    2048
#define EE    64
#define NTOK  8192
#define KS    2                 // k-split
#define KRANGE (DD / KS)        // 1024 k per gemm block
#define KC    32                // k per macro (= one MFMA K)
#define NM    (KRANGE / KC)     // 32 macros
#define MT    32                // tokens per gemm block

#define KPAD  2056              // Bt row stride (bf16 elems), 16B-aligned rows

// Output layout (all read back as float32 by harness):
#define PROB_OFF 0
#define IDX_OFF  524288
#define MASK_OFF 540672
#define MASK_K_STRIDE (NTOK * EE)
// Bt (split/transposed w) scratch lives in d_out's mask region: the epilogue
// fully overwrites that region afterwards (stream-ordered), so it's free.
#define BT_FLOAT_OFF 540672

#define GAP_THRESH 1e-3f        // ~50x the worst-case 3xbf16 z-error

typedef float f32x4 __attribute__((ext_vector_type(4)));
typedef short s16x8 __attribute__((ext_vector_type(8)));
typedef short s16x4 __attribute__((ext_vector_type(4)));

// Exact split: x = hi + lo with hi = truncate-to-bf16(x) (error-free as
// stored), lo = bf16(x - hi) (residual exact in fp32, then truncated).
// Dropped term lo*lo' ~ 2^-16 relative.
__device__ __forceinline__ void split_bf16(float x, short& h, short& l) {
  const unsigned u = __float_as_uint(x);
  h = (short)(u >> 16);
  const float r = x - __uint_as_float(u & 0xffff0000u);
  l = (short)(__float_as_uint(r) >> 16);
}

// ---------------------------------------------------------------------------
// Kernel 0: split+transpose w into Bt[h:128 rows][l:128 rows], row = output
// col n (0..63 gate, 64..127 noise), [n][k] bf16 row-major, stride KPAD.
// 1 MB total, written once into d_out scratch.
// ---------------------------------------------------------------------------
__global__ __launch_bounds__(256) void wt_kernel(
    const float* __restrict__ wg, const float* __restrict__ wn,
    unsigned short* __restrict__ bt)
{
  const int n  = blockIdx.x;              // 0..127
  const float* __restrict__ w = (n < EE) ? (wg + n) : (wn + (n - EE));
  const int k0 = threadIdx.x * 8;

  short h[8], l[8];
#pragma unroll
  for (int j = 0; j < 8; ++j)
    split_bf16(w[(size_t)(k0 + j) * EE], h[j], l[j]);

  s16x8 vh = {h[0], h[1], h[2], h[3], h[4], h[5], h[6], h[7]};
  s16x8 vl = {l[0], l[1], l[2], l[3], l[4], l[5], l[6], l[7]};
  *reinterpret_cast<s16x8*>(bt + (size_t)n * KPAD + k0)         = vh;
  *reinterpret_cast<s16x8*>(bt + (size_t)(128 + n) * KPAD + k0) = vl;
}

// ---------------------------------------------------------------------------
// Kernel 1: MFMA GEMM (3xBF16). Block 256 thr = 4 waves; block tile
// 32 tokens x 128 cols; wave tile 32 x 32 (2 m-tiles x 2 n-tiles of 16).
// Per macro per wave: 8 ds_read_b128 (A h/l x2 + B h/l x2) + 12 MFMA
// (3 split-products x 4 tiles). LDS single-buffer, 2-barrier, VGPR
// prefetch 1 macro ahead (R8-proven). x staged fp32->split in-kernel;
// B copied from pre-split Bt. KS=2 partials (fp32) -> 8 MB ws.
// A/B LDS rows padded to 40 bf16 (80 B) -> 2-way-max bank aliasing (free).
// Fragment layouts (m89/m92-verified): A[m=lane&15][k=quad*8+j],
// B[n=lane&15][k=quad*8+j] from [n][k] rows, C col=lane&15 row=quad*4+reg.
// ---------------------------------------------------------------------------
__global__ __launch_bounds__(256) void router_gemm(
    const float* __restrict__ x,           // [NTOK][DD]
    const unsigned short* __restrict__ bt, // [256][KPAD] (h rows, then l rows)
    float* __restrict__ part)              // [NTOK][KS][2*EE]
{
  __shared__ unsigned short lds[12800];    // 25600 B
  const int AH = 0, AL = 1280, BH = 2560, BL = 7680;   // bf16-elem offsets

  const int tid  = threadIdx.x;
  const int wid  = tid >> 6;
  const int lane = tid & 63;
  const int quad = lane >> 4;
  const int l15  = lane & 15;
  const int wn0  = wid * 32;               // this wave's n-quarter

  const int tok0   = blockIdx.x * MT;
  const int ks     = blockIdx.y;
  const int k0base = ks * KRANGE;

  // staging roles
  const int ar  = tid >> 3;                // A row 0..31
  const int akq = (tid & 7) * 4;           // A k-offset (float4)
  const int bn  = tid >> 1;                // B row 0..127
  const int bh2 = (tid & 1) * 16;          // B k-half (16 bf16)

  const float* __restrict__ xsrc = x + (size_t)(tok0 + ar) * DD + k0base + akq;
  const unsigned short* __restrict__ bts_h = bt + (size_t)bn * KPAD + k0base + bh2;
  const unsigned short* __restrict__ bts_l = bt + (size_t)(128 + bn) * KPAD + k0base + bh2;

  f32x4 acc[2][2];
#pragma unroll
  for (int mt = 0; mt < 2; ++mt)
#pragma unroll
    for (int nt = 0; nt < 2; ++nt) acc[mt][nt] = (f32x4){0.f, 0.f, 0.f, 0.f};

  // prefetch macro 0
  float4 pa = *reinterpret_cast<const float4*>(xsrc);
  s16x8 pb0 = *reinterpret_cast<const s16x8*>(bts_h);
  s16x8 pb1 = *reinterpret_cast<const s16x8*>(bts_h + 8);
  s16x8 pb2 = *reinterpret_cast<const s16x8*>(bts_l);
  s16x8 pb3 = *reinterpret_cast<const s16x8*>(bts_l + 8);

  for (int m = 0; m < NM; ++m) {
    // ---- write staged macro m into LDS ----
    short h0, h1, h2, h3, l0, l1, l2, l3;
    split_bf16(pa.x, h0, l0); split_bf16(pa.y, h1, l1);
    split_bf16(pa.z, h2, l2); split_bf16(pa.w, h3, l3);
    s16x4 vh = {h0, h1, h2, h3};
    s16x4 vl = {l0, l1, l2, l3};
    *reinterpret_cast<s16x4*>(&lds[AH + ar * 40 + akq]) = vh;
    *reinterpret_cast<s16x4*>(&lds[AL + ar * 40 + akq]) = vl;
    *reinterpret_cast<s16x8*>(&lds[BH + bn * 40 + bh2])     = pb0;
    *reinterpret_cast<s16x8*>(&lds[BH + bn * 40 + bh2 + 8]) = pb1;
    *reinterpret_cast<s16x8*>(&lds[BL + bn * 40 + bh2])     = pb2;
    *reinterpret_cast<s16x8*>(&lds[BL + bn * 40 + bh2 + 8]) = pb3;

    // ---- prefetch macro m+1 (in flight across this macro's compute) ----
    if (m + 1 < NM) {
      const int ko = (m + 1) * KC;
      pa  = *reinterpret_cast<const float4*>(xsrc + ko);
      pb0 = *reinterpret_cast<const s16x8*>(bts_h + ko);
      pb1 = *reinterpret_cast<const s16x8*>(bts_h + ko + 8);
      pb2 = *reinterpret_cast<const s16x8*>(bts_l + ko);
      pb3 = *reinterpret_cast<const s16x8*>(bts_l + ko + 8);
    }
    __builtin_amdgcn_sched_barrier(0);   // don't sink the prefetch
    __syncthreads();                     // tile m visible

    // ---- compute macro m (LDS-only operands) ----
    s16x8 af[2], al[2], bf[2], bl[2];
#pragma unroll
    for (int mt = 0; mt < 2; ++mt) {
      const int row = mt * 16 + l15;
      af[mt] = *reinterpret_cast<const s16x8*>(&lds[AH + row * 40 + quad * 8]);
      al[mt] = *reinterpret_cast<const s16x8*>(&lds[AL + row * 40 + quad * 8]);
    }
#pragma unroll
    for (int nt = 0; nt < 2; ++nt) {
      const int row = wn0 + nt * 16 + l15;
      bf[nt] = *reinterpret_cast<const s16x8*>(&lds[BH + row * 40 + quad * 8]);
      bl[nt] = *reinterpret_cast<const s16x8*>(&lds[BL + row * 40 + quad * 8]);
    }
#pragma unroll
    for (int mt = 0; mt < 2; ++mt)
#pragma unroll
      for (int nt = 0; nt < 2; ++nt) {
        acc[mt][nt] = __builtin_amdgcn_mfma_f32_16x16x32_bf16(af[mt], bf[nt], acc[mt][nt], 0, 0, 0);
        acc[mt][nt] = __builtin_amdgcn_mfma_f32_16x16x32_bf16(af[mt], bl[nt], acc[mt][nt], 0, 0, 0);
        acc[mt][nt] = __builtin_amdgcn_mfma_f32_16x16x32_bf16(al[mt], bf[nt], acc[mt][nt], 0, 0, 0);
      }
    __syncthreads();                     // readers done before next write
  }

  // ---- store fp32 partials [t][KS][128]; C: col=lane&15, row=quad*4+reg ----
#pragma unroll
  for (int mt = 0; mt < 2; ++mt)
#pragma unroll
    for (int nt = 0; nt < 2; ++nt) {
      const int col = wn0 + nt * 16 + l15;
#pragma unroll
      for (int r = 0; r < 4; ++r) {
        const int t = tok0 + mt * 16 + quad * 4 + r;
        part[((size_t)t * KS + ks) * (2 * EE) + col] = acc[mt][nt][r];
      }
    }
}

// ---------------------------------------------------------------------------
// Kernel 2: epilogue. One wave per token: sum KS partials, softplus-noise,
// top-3 gap check; near-ties (gap < GAP_THRESH) take a wave-uniform exact
// fp32 recompute (lane=expert, coalesced w reads). Then top-2 (jax tie
// semantics), softmax over 2, scatter probs + indices + one-hot masks.
// ---------------------------------------------------------------------------
__global__ __launch_bounds__(256) void router_epilogue(
    const float* __restrict__ part,      // [NTOK][KS][2*EE]
    const float* __restrict__ noise_eps, // [NTOK][EE]
    const float* __restrict__ x,         // [NTOK][DD]
    const float* __restrict__ wg,        // [DD][EE]
    const float* __restrict__ wn,        // [DD][EE]
    float* __restrict__ out)
{
  const int t    = blockIdx.x * 4 + (threadIdx.x >> 6);
  const int lane = threadIdx.x & 63;

  const float* p = part + (size_t)t * KS * (2 * EE);
  float g    = p[lane]      + p[128 + lane];
  float nraw = p[EE + lane] + p[128 + EE + lane];
  const float ep = noise_eps[(size_t)t * EE + lane];

  float sp = fmaxf(nraw, 0.0f) + log1pf(expf(-fabsf(nraw)));
  float z  = fmaf(sp, ep, g);

  // top-1 / top-2 butterflies (all lanes converge)
  float v1 = z; int i1 = lane;
#pragma unroll
  for (int off = 32; off >= 1; off >>= 1) {
    const float ov = __shfl_xor(v1, off, 64);
    const int   oi = __shfl_xor(i1, off, 64);
    if (ov > v1 || (ov == v1 && oi < i1)) { v1 = ov; i1 = oi; }
  }
  float v2 = (lane == i1) ? -INFINITY : z; int i2 = lane;
#pragma unroll
  for (int off = 32; off >= 1; off >>= 1) {
    const float ov = __shfl_xor(v2, off, 64);
    const int   oi = __shfl_xor(i2, off, 64);
    if (ov > v2 || (ov == v2 && oi < i2)) { v2 = ov; i2 = oi; }
  }
  // top-3 value only (for the gap check)
  float v3 = (lane == i1 || lane == i2) ? -INFINITY : z;
#pragma unroll
  for (int off = 32; off >= 1; off >>= 1)
    v3 = fmaxf(v3, __shfl_xor(v3, off, 64));

  if ((v1 - v2 < GAP_THRESH) || (v2 - v3 < GAP_THRESH)) {
    // exact fp32 recompute for this token (wave-uniform branch)
    float ge = 0.0f, ne = 0.0f;
    const float* __restrict__ xr = x + (size_t)t * DD;
    for (int k = 0; k < DD; k += 4) {
      const float4 xv = *reinterpret_cast<const float4*>(xr + k);
      ge = fmaf(xv.x, wg[(size_t)(k + 0) * EE + lane], ge);
      ne = fmaf(xv.x, wn[(size_t)(k + 0) * EE + lane], ne);
      ge = fmaf(xv.y, wg[(size_t)(k + 1) * EE + lane], ge);
      ne = fmaf(xv.y, wn[(size_t)(k + 1) * EE + lane], ne);
      ge = fmaf(xv.z, wg[(size_t)(k + 2) * EE + lane], ge);
      ne = fmaf(xv.z, wn[(size_t)(k + 2) * EE + lane], ne);
      ge = fmaf(xv.w, wg[(size_t)(k + 3) * EE + lane], ge);
      ne = fmaf(xv.w, wn[(size_t)(k + 3) * EE + lane], ne);
    }
    sp = fmaxf(ne, 0.0f) + log1pf(expf(-fabsf(ne)));
    z  = fmaf(sp, ep, ge);
    v1 = z; i1 = lane;
#pragma unroll
    for (int off = 32; off >= 1; off >>= 1) {
      const float ov = __shfl_xor(v1, off, 64);
      const int   oi = __shfl_xor(i1, off, 64);
      if (ov > v1 || (ov == v1 && oi < i1)) { v1 = ov; i1 = oi; }
    }
    v2 = (lane == i1) ? -INFINITY : z; i2 = lane;
#pragma unroll
    for (int off = 32; off >= 1; off >>= 1) {
      const float ov = __shfl_xor(v2, off, 64);
      const int   oi = __shfl_xor(i2, off, 64);
      if (ov > v2 || (ov == v2 && oi < i2)) { v2 = ov; i2 = oi; }
    }
  }

  const float e2 = expf(v2 - v1);
  const float denom = 1.0f + e2;
  const float p1 = 1.0f / denom;
  const float p2 = e2 / denom;

  out[PROB_OFF + (size_t)t * EE + lane] =
      (lane == i1) ? p1 : ((lane == i2) ? p2 : 0.0f);

  if (lane == 0) {
    out[IDX_OFF + t * 2 + 0] = (float)i1;
    out[IDX_OFF + t * 2 + 1] = (float)i2;
  }

  out[MASK_OFF + 0 * MASK_K_STRIDE + (size_t)t * EE + lane] = (lane == i1) ? 1.0f : 0.0f;
  out[MASK_OFF + 1 * MASK_K_STRIDE + (size_t)t * EE + lane] = (lane == i2) ? 1.0f : 0.0f;
}

// ---------------------------------------------------------------------------
extern "C" void kernel_launch(void* const* d_in, const int* in_sizes, int n_in,
                              void* d_out, int out_size, void* d_ws, size_t ws_size,
                              hipStream_t stream) {
  const float* x   = (const float*)d_in[0];
  const float* eps = (const float*)d_in[1];
  const float* wg  = (const float*)d_in[2];
  const float* wn  = (const float*)d_in[3];
  float* out = (float*)d_out;
  float* ws  = (float*)d_ws;   // KS * 4 MB = 8 MB fp32 partials

  // Bt scratch in d_out's mask region (1.05 MB used of 4 MB; epilogue
  // rewrites the whole region afterwards, stream-ordered).
  unsigned short* bt = (unsigned short*)(out + BT_FLOAT_OFF);

  wt_kernel<<<dim3(128), dim3(256), 0, stream>>>(wg, wn, bt);
  router_gemm<<<dim3(NTOK / MT, KS), dim3(256), 0, stream>>>(x, bt, ws);
  router_epilogue<<<dim3(NTOK / 4), dim3(256), 0, stream>>>(ws, eps, x, wg, wn, out);
}